// Round 3
// baseline (243.114 us; speedup 1.0000x reference)
//
#include <hip/hip_runtime.h>

// LIF scan over T=16: mem_t = beta*mem + x_t - spk_{t-1}; spk_t = (mem_t - 1) > 0.
// Neurons independent -> 1 thread owns 4 neurons across all T.
//
// R6: R3/R4/R5 scheduling interventions all neutral (242-256 us) -> per-wave
// MLP was never the limiter. Counters show the real story: FETCH=65 MB (half
// the input served from the 256 MB L3) but WRITE=131 MB = the FULL output
// forced to HBM every dispatch, because __builtin_nontemporal_store bypasses
// L2/L3. The harness re-launches into the SAME output buffer: with plain
// cacheable stores, iteration 2+ dirty-hits resident L3 lines and the write
// stream stops reaching HBM entirely (input 134 MB + output 134 MB ~ L3
// capacity). Single-variable change vs R5: NT store -> plain store.
// Mechanism check: WRITE_SIZE must drop well below 131 MB.

constexpr int   T      = 16;
constexpr float BETA   = 0.9f;
constexpr float THRESH = 1.0f;

typedef float f4 __attribute__((ext_vector_type(4)));

__global__ __launch_bounds__(256, 4) void lif_kernel(const float* __restrict__ x,
                                                     float* __restrict__ out,
                                                     int n_per_t) {
    // No FMA contraction: must match numpy's two-rounding fp32 exactly, else
    // ~1-ulp drift flips spikes at the threshold (absmax = 1.0 cascades).
#pragma clang fp contract(off)
    const int idx = (blockIdx.x * blockDim.x + threadIdx.x) * 4;
    if (idx >= n_per_t) return;

    f4 v[T];  // holds x_t on the way in, spk_t on the way out

    // Phase 1: 16 independent loads issued back-to-back (coalesced per wave,
    // streams 8 MB apart).
#pragma unroll
    for (int t = 0; t < T; ++t) {
        v[t] = *reinterpret_cast<const f4*>(x + (size_t)t * (size_t)n_per_t + (size_t)idx);
    }

    // Keep R5's fence (neutral perf, single-variable discipline vs R5).
    asm volatile("" : "+v"(v[0]), "+v"(v[1]), "+v"(v[2]), "+v"(v[3]),
                      "+v"(v[4]), "+v"(v[5]), "+v"(v[6]), "+v"(v[7]),
                      "+v"(v[8]), "+v"(v[9]), "+v"(v[10]), "+v"(v[11]),
                      "+v"(v[12]), "+v"(v[13]), "+v"(v[14]), "+v"(v[15]));

    // Phase 2: the sequential recurrence, pure registers.
    f4 mem = (f4)(0.f);
    f4 spk = (f4)(0.f);
#pragma unroll
    for (int t = 0; t < T; ++t) {
#pragma unroll
        for (int j = 0; j < 4; ++j) {
            mem[j] = BETA * mem[j] + v[t][j] - spk[j] * THRESH;
            spk[j] = (mem[j] - THRESH) > 0.f ? 1.f : 0.f;
        }
        v[t] = spk;
    }

    // Phase 3: 16 PLAIN stores. Cacheable -> write-allocate into L2/L3; the
    // repeatedly-rewritten output buffer dirty-hits in Infinity Cache instead
    // of forcing 131 MB/dispatch onto the HBM write path (what NT stores did).
#pragma unroll
    for (int t = 0; t < T; ++t) {
        *reinterpret_cast<f4*>(out + (size_t)t * (size_t)n_per_t + (size_t)idx) = v[t];
    }
}

extern "C" void kernel_launch(void* const* d_in, const int* in_sizes, int n_in,
                              void* d_out, int out_size, void* d_ws, size_t ws_size,
                              hipStream_t stream) {
    const float* x   = (const float*)d_in[0];
    float*       out = (float*)d_out;

    const int total   = in_sizes[0];      // 33,554,432
    const int n_per_t = total / T;        // 2,097,152 (divisible by 4)
    const int threads = n_per_t / 4;      // 524,288

    dim3 block(256);
    dim3 grid((threads + block.x - 1) / block.x);  // 2048 blocks
    lif_kernel<<<grid, block, 0, stream>>>(x, out, n_per_t);
}

// Round 4
// 235.071 us; speedup vs baseline: 1.0342x; 1.0342x over previous
//
#include <hip/hip_runtime.h>

// LIF scan over T=16: mem_t = beta*mem + x_t - spk_{t-1}; spk_t = (mem_t - 1) > 0.
// Neurons independent -> 1 thread owns 8 neurons (2 dense f4 chunks) across all T.
//
// R7: post-mortem of R4-R6: every explicit fence cost ~25% on dispatch time
// (84 us no-fence vs 103-112 us all fence variants) -- the asm-operand fence
// forces a vmcnt(0) full drain (wave waits for slowest of 16 loads) which is
// strictly worse than the compiler's rolling MLP~4 schedule. VGPR stuck at 40
// across all attempts; Little's law shows ~128 KB/CU in flight vs ~10 KB
// needed -> latency was NEVER the limiter. Kernel streams at 3.2 TB/s logical
// = 51% of copy ceiling with VALUBusy 3%: fabric/DRAM pattern bound.
// R7 changes: (1) REVERT all fences (back to measured-best R3 schedule);
// (2) 2x per-thread span: two dense f4 chunks 1024 floats apart -> block
// covers 8 KB contiguous per plane (longer sequential runs per DRAM stream),
// wave count halves (16 waves/CU, still >> latency needs), per-wave MLP bytes
// double, and the A/B dual recurrence adds VALU ILP. NT stores kept (matches
// best-measured config; write stream always reaches fabric regardless).

constexpr int   T      = 16;
constexpr float BETA   = 0.9f;
constexpr float THRESH = 1.0f;

typedef float f4 __attribute__((ext_vector_type(4)));

__global__ __launch_bounds__(256) void lif_kernel(const float* __restrict__ x,
                                                  float* __restrict__ out,
                                                  int n_per_t) {
    // No FMA contraction: must match numpy's two-rounding fp32 exactly, else
    // ~1-ulp drift flips spikes at the threshold (absmax = 1.0 cascades).
#pragma clang fp contract(off)
    // Block covers 2048 floats per plane: chunk A = first 1024 (dense across
    // the block's threads), chunk B = second 1024. Both fully coalesced b128.
    const int base = blockIdx.x * 2048 + threadIdx.x * 4;
    const int idxA = base;
    const int idxB = base + 1024;
    if (idxB >= n_per_t) return;

    f4 va[T], vb[T];  // x_t on the way in, spk_t on the way out

    // Loads: 32 independent dense streams; let the compiler roll its own
    // pipeline (fenced variants measured 25% slower).
#pragma unroll
    for (int t = 0; t < T; ++t) {
        const size_t p = (size_t)t * (size_t)n_per_t;
        va[t] = *reinterpret_cast<const f4*>(x + p + (size_t)idxA);
        vb[t] = *reinterpret_cast<const f4*>(x + p + (size_t)idxB);
    }

    // Two independent recurrences, pure registers (ILP x2).
    f4 memA = (f4)(0.f), spkA = (f4)(0.f);
    f4 memB = (f4)(0.f), spkB = (f4)(0.f);
#pragma unroll
    for (int t = 0; t < T; ++t) {
#pragma unroll
        for (int j = 0; j < 4; ++j) {
            memA[j] = BETA * memA[j] + va[t][j] - spkA[j] * THRESH;
            spkA[j] = (memA[j] - THRESH) > 0.f ? 1.f : 0.f;
            memB[j] = BETA * memB[j] + vb[t][j] - spkB[j] * THRESH;
            spkB[j] = (memB[j] - THRESH) > 0.f ? 1.f : 0.f;
        }
        va[t] = spkA;
        vb[t] = spkB;
    }

    // Stores: nontemporal (write stream reaches fabric either way; NT matches
    // the best-measured config).
#pragma unroll
    for (int t = 0; t < T; ++t) {
        const size_t p = (size_t)t * (size_t)n_per_t;
        __builtin_nontemporal_store(va[t], reinterpret_cast<f4*>(out + p + (size_t)idxA));
        __builtin_nontemporal_store(vb[t], reinterpret_cast<f4*>(out + p + (size_t)idxB));
    }
}

extern "C" void kernel_launch(void* const* d_in, const int* in_sizes, int n_in,
                              void* d_out, int out_size, void* d_ws, size_t ws_size,
                              hipStream_t stream) {
    const float* x   = (const float*)d_in[0];
    float*       out = (float*)d_out;

    const int total   = in_sizes[0];      // 33,554,432
    const int n_per_t = total / T;        // 2,097,152 (divisible by 2048)
    const int blocks  = n_per_t / 2048;   // 1024 blocks, 256 threads, 8 floats/thread

    lif_kernel<<<dim3(blocks), dim3(256), 0, stream>>>(x, out, n_per_t);
}

// Round 5
// 230.086 us; speedup vs baseline: 1.0566x; 1.0217x over previous
//
#include <hip/hip_runtime.h>

// LIF scan over T=16: mem_t = beta*mem + x_t - spk_{t-1}; spk_t = (mem_t - 1) > 0.
// Neurons independent -> 1 thread owns 16 neurons (4 dense f4 chunks) across all T.
//
// R8 (envelope test): R4-R6 proved scheduling/fencing is a dead end (compiler's
// rolling MLP~4 is optimal; every fence cost 25%; latency fully covered). R7's
// +3% from doubling run length is the only live lever. This round maxes it:
// 4 chunks/thread spaced 1024 floats -> each block covers 16 KB contiguous per
// plane (512 blocks, 8 waves/CU -- still 2-4x the in-flight bytes needed), and
// switches NT->plain stores (R5 vs R6 measured plain ~4% faster; R6 proved NT
// has zero traffic benefit: WRITE_SIZE identical, L3 is write-through for this
// stream). If this lands >=80 us/dispatch the structural envelope (~3.3 TB/s
// logical for a 1:1 R/W 32-stream pattern) is established.

constexpr int   T      = 16;
constexpr float BETA   = 0.9f;
constexpr float THRESH = 1.0f;

typedef float f4 __attribute__((ext_vector_type(4)));

__global__ __launch_bounds__(256) void lif_kernel(const float* __restrict__ x,
                                                  float* __restrict__ out,
                                                  int n_per_t) {
    // No FMA contraction: must match numpy's two-rounding fp32 exactly, else
    // ~1-ulp drift flips spikes at the threshold (absmax = 1.0 cascades).
#pragma clang fp contract(off)
    // Block covers 4096 consecutive floats per plane in 4 chunks of 1024;
    // every chunk is a dense, fully-coalesced b128 access across the block.
    const int base = blockIdx.x * 4096 + threadIdx.x * 4;
    if (base + 3072 + 4 > n_per_t) return;

    f4 v0[T], v1[T], v2[T], v3[T];  // x_t in, spk_t out

    // Loads: 64 independent dense streams; compiler rolls its own pipeline
    // (every explicit fence variant measured 25% slower, R4-R6).
#pragma unroll
    for (int t = 0; t < T; ++t) {
        const size_t p = (size_t)t * (size_t)n_per_t + (size_t)base;
        v0[t] = *reinterpret_cast<const f4*>(x + p);
        v1[t] = *reinterpret_cast<const f4*>(x + p + 1024);
        v2[t] = *reinterpret_cast<const f4*>(x + p + 2048);
        v3[t] = *reinterpret_cast<const f4*>(x + p + 3072);
    }

    // Four independent recurrences, pure registers (ILP x4).
    f4 m0 = (f4)(0.f), s0 = (f4)(0.f);
    f4 m1 = (f4)(0.f), s1 = (f4)(0.f);
    f4 m2 = (f4)(0.f), s2 = (f4)(0.f);
    f4 m3 = (f4)(0.f), s3 = (f4)(0.f);
#pragma unroll
    for (int t = 0; t < T; ++t) {
#pragma unroll
        for (int j = 0; j < 4; ++j) {
            m0[j] = BETA * m0[j] + v0[t][j] - s0[j] * THRESH;
            s0[j] = (m0[j] - THRESH) > 0.f ? 1.f : 0.f;
            m1[j] = BETA * m1[j] + v1[t][j] - s1[j] * THRESH;
            s1[j] = (m1[j] - THRESH) > 0.f ? 1.f : 0.f;
            m2[j] = BETA * m2[j] + v2[t][j] - s2[j] * THRESH;
            s2[j] = (m2[j] - THRESH) > 0.f ? 1.f : 0.f;
            m3[j] = BETA * m3[j] + v3[t][j] - s3[j] * THRESH;
            s3[j] = (m3[j] - THRESH) > 0.f ? 1.f : 0.f;
        }
        v0[t] = s0;
        v1[t] = s1;
        v2[t] = s2;
        v3[t] = s3;
    }

    // Stores: PLAIN (cacheable). NT measured no traffic benefit (R6) and ~4%
    // slower than plain in the fenced A/B (R5 vs R6); plain lets L2 aggregate.
#pragma unroll
    for (int t = 0; t < T; ++t) {
        const size_t p = (size_t)t * (size_t)n_per_t + (size_t)base;
        *reinterpret_cast<f4*>(out + p)        = v0[t];
        *reinterpret_cast<f4*>(out + p + 1024) = v1[t];
        *reinterpret_cast<f4*>(out + p + 2048) = v2[t];
        *reinterpret_cast<f4*>(out + p + 3072) = v3[t];
    }
}

extern "C" void kernel_launch(void* const* d_in, const int* in_sizes, int n_in,
                              void* d_out, int out_size, void* d_ws, size_t ws_size,
                              hipStream_t stream) {
    const float* x   = (const float*)d_in[0];
    float*       out = (float*)d_out;

    const int total   = in_sizes[0];      // 33,554,432
    const int n_per_t = total / T;        // 2,097,152 (divisible by 4096)
    const int blocks  = n_per_t / 4096;   // 512 blocks, 256 threads, 16 floats/thread

    lif_kernel<<<dim3(blocks), dim3(256), 0, stream>>>(x, out, n_per_t);
}